// Round 16
// baseline (396.998 us; speedup 1.0000x reference)
//
#include <hip/hip_runtime.h>
#include <hip/hip_bf16.h>

#define NN 100000
#define EE 800000
#define HID 128
#define NH 4
#define CH 32
#define NL 3
#define NOUT 5
#define NEG_SLOPE 0.2f
#define LN_EPS 1e-5f
#define GCAP 128           // LDS-cached edges per 8-node wave group (real edges only)
#define NB_SCAN 98         // ceil((NN+1)/1024)
#define HQ (HID / 2)       // u32-packed bf16 pairs per row
#define WB_LSZ 9216        // u32 per layer of packed B-frags: 4ks*9ct*64lane*4
#define HB16 196           // hist blocks: ceil(EE/4096), 16 edges/thread
#define SB16 196           // scatter blocks, 16 edges/thread
#define NG64 1563          // in_gemm blocks = ceil(NN/64)

typedef unsigned int u32;
typedef __attribute__((ext_vector_type(8))) short bf16x8;
typedef __attribute__((ext_vector_type(4))) float f32x4;

static __device__ __forceinline__ float bflo(u32 r) { return __uint_as_float(r << 16); }
static __device__ __forceinline__ float bfhi(u32 r) { return __uint_as_float(r & 0xffff0000u); }
static __device__ __forceinline__ unsigned short f2bf(float x) {
    union U { __hip_bfloat16 b; unsigned short s; } u;
    u.b = __float2bfloat16(x);
    return u.s;
}
static __device__ __forceinline__ u32 pack2(float a, float b) {
    return (u32)f2bf(a) | ((u32)f2bf(b) << 16);
}
static __device__ __forceinline__ float lrelu(float x) {
    return x > 0.f ? x : NEG_SLOPE * x;
}

// ---------------------------------------------------------------------------
// Fused dispatch A: hist (blocks 0..HB16-1, 16 edges/thread) || weight prep.
// ---------------------------------------------------------------------------
__global__ void hist_prep_kernel(const int* __restrict__ ei, int* __restrict__ cnt,
                                 u32* __restrict__ slot,
                                 const float* __restrict__ We, const float* __restrict__ a_e,
                                 float* __restrict__ wedot,
                                 const float* __restrict__ Win, const float* __restrict__ b_in,
                                 const float* __restrict__ Wg, float* __restrict__ wf,
                                 const float* __restrict__ a_src, const float* __restrict__ a_dst,
                                 u32* __restrict__ wb, float* __restrict__ wga) {
    int b = blockIdx.x, t = threadIdx.x;
    if (b < HB16) {
        int e0 = b * 4096 + t;
        #pragma unroll
        for (int k = 0; k < 16; k++) {
            int e = e0 + k * 256;
            if (e < EE) {
                int d = ei[EE + e];
                int s = atomicAdd(&cnt[d], 1);
                slot[e] = ((u32)d << 8) | (u32)s;
            }
        }
        return;
    }
    if (b == HB16) {
        if (t < NL * NH) {
            int l = t >> 2, hh = t & 3;
            float s = 0.f;
            #pragma unroll
            for (int c = 0; c < CH; c++)
                s += We[l * HID + hh * CH + c] * a_e[l * HID + hh * CH + c];
            wedot[t] = s;
        }
        // WgA0[m][j] = head-masked (Wg0 @ Aext): j<4 src head j, j>=4 dst head j-4
        for (int i = t; i < HID * 8; i += 256) {
            int m = i >> 3, j = i & 7;
            int hh = j & 3;
            const float* a = (j < 4) ? (a_src + hh * CH) : (a_dst + hh * CH);
            const float* wrow = Wg + (size_t)m * HID + hh * CH;
            float s = 0.f;
            #pragma unroll
            for (int c = 0; c < CH; c++) s += wrow[c] * a[c];
            wga[i] = s;
        }
        return;
    }
    if (b < HB16 + 18) {
        // wfuse: wf[r][c] = sum_k (r<32 ? Win[r][k] : b_in[k]) * Wg0[k][c]
        int idx = (b - HB16 - 1) * 256 + t;
        if (idx >= 33 * HID) return;
        int r = idx >> 7, c = idx & 127;
        float acc = 0.f;
        for (int k = 0; k < HID; k++) {
            float a = (r < 32) ? Win[r * HID + k] : b_in[k];
            acc += a * Wg[(size_t)k * HID + c];
        }
        wf[r * HID + c] = acc;
        return;
    }
    // pack Wg[1..2] (+ head-masked al columns as 9th col-tile) into B-frags
    {
        int idx = (b - HB16 - 18) * 256 + t;   // 0..4607
        if (idx >= 2 * 2304) return;
        int l = idx / 2304;
        int rem = idx % 2304;
        int ks = rem / 576;
        int ct = (rem % 576) / 64;
        int lane = rem % 64;
        int q = lane >> 4, n = lane & 15;
        const float* W = Wg + (size_t)(l + 1) * HID * HID;
        float v[8];
        if (ct < 8) {
            #pragma unroll
            for (int j = 0; j < 8; j++) {
                int k = ks * 32 + q * 8 + j;
                v[j] = W[(size_t)k * HID + ct * 16 + n];
            }
        } else {
            #pragma unroll
            for (int j = 0; j < 8; j++) v[j] = 0.f;
            if (n < 8) {
                const float* a = (n < 4) ? (a_src + (l + 1) * HID + (n & 3) * CH)
                                         : (a_dst + (l + 1) * HID + (n & 3) * CH);
                #pragma unroll
                for (int j = 0; j < 8; j++) {
                    int k = ks * 32 + q * 8 + j;
                    const float* wrow = W + (size_t)k * HID + (n & 3) * CH;
                    float s = 0.f;
                    for (int c = 0; c < CH; c++) s += wrow[c] * a[c];
                    v[j] = s;
                }
            }
        }
        u32* dst = wb + (size_t)l * WB_LSZ + (size_t)((ks * 9 + ct) * 64 + lane) * 4;
        dst[0] = pack2(v[0], v[1]); dst[1] = pack2(v[2], v[3]);
        dst[2] = pack2(v[4], v[5]); dst[3] = pack2(v[6], v[7]);
    }
}

// ---------------------------------------------------------------------------
// Fused dispatch B: single-pass scan (decoupled lookback) || prep2.
// ---------------------------------------------------------------------------
__global__ __launch_bounds__(1024) void scan_prep2_kernel(const int* __restrict__ cnt,
        int* __restrict__ rowptr, int* __restrict__ sums, int* __restrict__ prefixes,
        int* __restrict__ flags,
        const float* __restrict__ Win, const float* __restrict__ b_in,
        const float* __restrict__ wga, float* __restrict__ wf, u32* __restrict__ wb2) {
    if (blockIdx.x >= NB_SCAN) {
        int b = blockIdx.x - NB_SCAN;        // 0..17
        int lane = threadIdx.x;
        if (lane >= 64) return;
        int q = lane >> 4, n = lane & 15;
        if (b == 17) {
            if (lane < 8) {
                float s = 0.f;
                for (int m = 0; m < HID; m++) s += b_in[m] * wga[m * 8 + lane];
                wf[33 * HID + lane] = s;     // bfA
            }
            return;
        }
        float v[8];
        if (b < 8) {
            #pragma unroll
            for (int j = 0; j < 8; j++) v[j] = Win[(q * 8 + j) * HID + b * 16 + n];
        } else if (b < 16) {
            int ct = b - 8;
            #pragma unroll
            for (int j = 0; j < 8; j++) v[j] = wf[(q * 8 + j) * HID + ct * 16 + n];
        } else {                             // al tile: Win @ WgA0
            #pragma unroll
            for (int j = 0; j < 8; j++) v[j] = 0.f;
            if (n < 8) {
                #pragma unroll
                for (int j = 0; j < 8; j++) {
                    const float* wrow = Win + (q * 8 + j) * HID;
                    float s = 0.f;
                    for (int m = 0; m < HID; m++) s += wrow[m] * wga[m * 8 + n];
                    v[j] = s;
                }
            }
        }
        u32* dst = wb2 + (size_t)(b * 64 + lane) * 4;
        dst[0] = pack2(v[0], v[1]); dst[1] = pack2(v[2], v[3]);
        dst[2] = pack2(v[4], v[5]); dst[3] = pack2(v[6], v[7]);
        return;
    }
    // --- scan block ---
    __shared__ int ws[16];
    __shared__ int bprefix;
    int b = blockIdx.x;
    int gid = b * 1024 + threadIdx.x;
    int v = (gid < NN) ? cnt[gid] : 0;
    int lane = threadIdx.x & 63, wid = threadIdx.x >> 6;
    int s = v;
    #pragma unroll
    for (int off = 1; off < 64; off <<= 1) {
        int t2 = __shfl_up(s, off, 64);
        if (lane >= off) s += t2;
    }
    if (lane == 63) ws[wid] = s;
    __syncthreads();
    int add = 0;
    for (int w2 = 0; w2 < wid; w2++) add += ws[w2];
    int incl = s + add;                      // block-local inclusive
    if (threadIdx.x == 0) {
        int total = 0;
        for (int w2 = 0; w2 < 16; w2++) total += ws[w2];
        atomicExch(&sums[b], total);
        __threadfence();
        atomicExch(&flags[b], 1);
        int pfx = 0;
        for (int i = b - 1; i >= 0; i--) {
            int f;
            do { f = atomicAdd(&flags[i], 0); } while (f == 0);
            if (f == 2) { pfx += atomicAdd(&prefixes[i], 0); break; }
            pfx += atomicAdd(&sums[i], 0);
        }
        atomicExch(&prefixes[b], pfx + total);
        __threadfence();
        atomicExch(&flags[b], 2);
        bprefix = pfx;
    }
    __syncthreads();
    int pfx = bprefix;
    if (gid <= NN) rowptr[gid] = pfx + incl - v;   // exclusive
}

// ---------------------------------------------------------------------------
// Fused dispatch C: scatter (blocks 0..SB16-1, 16 edges/thread) || layer-0
// MFMA GEMM. xh stored bf16 (u32-packed).
// ---------------------------------------------------------------------------
__global__ __launch_bounds__(256) void scatter_ingemm_kernel(
        const int* __restrict__ ei, const float* __restrict__ ea,
        const int* __restrict__ rowptr, const u32* __restrict__ slot,
        uint2* __restrict__ edges,
        const float* __restrict__ x, const u32* __restrict__ wb2,
        const float* __restrict__ wf, const float* __restrict__ b_in,
        u32* __restrict__ h, u32* __restrict__ xh,
        float* __restrict__ al_s, float* __restrict__ al_d) {
    __shared__ u32 xsu[1024];                // used by the in_gemm branch only
    if (blockIdx.x < SB16) {
        int e0 = blockIdx.x * 4096 + threadIdx.x;
        #pragma unroll
        for (int k = 0; k < 16; k++) {
            int e = e0 + k * 256;
            if (e < EE) {
                u32 p = slot[e];
                int d = (int)(p >> 8);
                int pos = rowptr[d] + (int)(p & 255u);
                edges[pos] = make_uint2((u32)ei[e], __float_as_uint(ea[e]));
            }
        }
        return;
    }
    int t = threadIdx.x;
    int wv = t >> 6, lane = t & 63;
    int q = lane >> 4, n16 = lane & 15;
    int n0 = (blockIdx.x - SB16) * 64;
    // stage x -> bf16 A-frags
    {
        int row = t >> 2, qq = t & 3;
        int gr = n0 + row;
        int rt = row >> 4, m = row & 15;
        uint4 op = make_uint4(0u, 0u, 0u, 0u);
        if (gr < NN) {
            float4 vA = *(const float4*)&x[(size_t)gr * 32 + qq * 8];
            float4 vB = *(const float4*)&x[(size_t)gr * 32 + qq * 8 + 4];
            op.x = pack2(vA.x, vA.y); op.y = pack2(vA.z, vA.w);
            op.z = pack2(vB.x, vB.y); op.w = pack2(vB.z, vB.w);
        }
        *(uint4*)&xsu[(rt * 64 + qq * 16 + m) * 4] = op;
    }
    bf16x8 bwin[2], bwf[2], bal;
    #pragma unroll
    for (int cc = 0; cc < 2; cc++) {
        uint4 r0 = *(const uint4*)&wb2[(size_t)(((wv * 2 + cc)) * 64 + lane) * 4];
        uint4 r1 = *(const uint4*)&wb2[(size_t)((8 + wv * 2 + cc) * 64 + lane) * 4];
        bwin[cc] = __builtin_bit_cast(bf16x8, r0);
        bwf[cc]  = __builtin_bit_cast(bf16x8, r1);
    }
    {
        uint4 r = *(const uint4*)&wb2[(size_t)(16 * 64 + lane) * 4];
        bal = __builtin_bit_cast(bf16x8, r);
    }
    __syncthreads();
    f32x4 acch[4][2], accx[4][2], accal[4];
    #pragma unroll
    for (int rt = 0; rt < 4; rt++) {
        acch[rt][0] = (f32x4){0.f, 0.f, 0.f, 0.f};
        acch[rt][1] = (f32x4){0.f, 0.f, 0.f, 0.f};
        accx[rt][0] = (f32x4){0.f, 0.f, 0.f, 0.f};
        accx[rt][1] = (f32x4){0.f, 0.f, 0.f, 0.f};
        accal[rt]   = (f32x4){0.f, 0.f, 0.f, 0.f};
    }
    #pragma unroll
    for (int rt = 0; rt < 4; rt++) {
        uint4 araw = *(const uint4*)&xsu[(rt * 64 + lane) * 4];
        bf16x8 af = __builtin_bit_cast(bf16x8, araw);
        acch[rt][0] = __builtin_amdgcn_mfma_f32_16x16x32_bf16(af, bwin[0], acch[rt][0], 0, 0, 0);
        acch[rt][1] = __builtin_amdgcn_mfma_f32_16x16x32_bf16(af, bwin[1], acch[rt][1], 0, 0, 0);
        accx[rt][0] = __builtin_amdgcn_mfma_f32_16x16x32_bf16(af, bwf[0], accx[rt][0], 0, 0, 0);
        accx[rt][1] = __builtin_amdgcn_mfma_f32_16x16x32_bf16(af, bwf[1], accx[rt][1], 0, 0, 0);
        if (wv == 3)
            accal[rt] = __builtin_amdgcn_mfma_f32_16x16x32_bf16(af, bal, accal[rt], 0, 0, 0);
    }
    float bi[2], bfv[2];
    #pragma unroll
    for (int cc = 0; cc < 2; cc++) {
        int col = (wv * 2 + cc) * 16 + n16;
        bi[cc] = b_in[col];
        bfv[cc] = wf[32 * HID + col];
    }
    float bfa = (wv == 3 && n16 < 8) ? wf[33 * HID + n16] : 0.f;
    #pragma unroll
    for (int rt = 0; rt < 4; rt++) {
        #pragma unroll
        for (int reg = 0; reg < 4; reg++) {
            int row = n0 + rt * 16 + q * 4 + reg;
            #pragma unroll
            for (int cc = 0; cc < 2; cc++) {
                float v = acch[rt][cc][reg] + bi[cc];
                float vp = __shfl_xor(v, 1, 64);
                float u = accx[rt][cc][reg] + bfv[cc];
                float up = __shfl_xor(u, 1, 64);
                if (!(n16 & 1) && row < NN) {
                    int colp = (wv * 2 + cc) * 8 + (n16 >> 1);
                    h[(size_t)row * HQ + colp] = pack2(v, vp);
                    xh[(size_t)row * HQ + colp] = pack2(u, up);
                }
            }
            if (wv == 3 && row < NN && n16 < 8) {
                float v = accal[rt][reg] + bfa;
                if (n16 < 4) al_s[row * 4 + n16] = v;
                else         al_d[row * 4 + (n16 - 4)] = v;
            }
        }
    }
}

// ---------------------------------------------------------------------------
// Layers 1..2 via MFMA; LN stats reduced inline from the previous layer's
// partials buffer.
// ---------------------------------------------------------------------------
__global__ __launch_bounds__(256) void gemm_mfma_kernel(const u32* __restrict__ h,
        const u32* __restrict__ wb, u32* __restrict__ xh, const u32* __restrict__ g,
        const float* __restrict__ lnw, const float* __restrict__ lnb,
        const float* __restrict__ partials, u32* __restrict__ hout,
        float* __restrict__ al_s, float* __restrict__ al_d) {
    __shared__ u32 hsu[4096];                // 16KB, frag-ordered [rt][ks][lane][4]
    __shared__ float sred[8];
    int n0 = blockIdx.x * 64;
    int t = threadIdx.x;
    int wv = t >> 6, lane = t & 63;
    int q = lane >> 4, n16 = lane & 15;

    {
        const float4* pp = (const float4*)partials;
        float4 v0 = pp[t * 2], v1 = pp[t * 2 + 1];
        float s = v0.x + v0.z + v1.x + v1.z;
        float qq = v0.y + v0.w + v1.y + v1.w;
        #pragma unroll
        for (int off = 1; off <= 32; off <<= 1) {
            s += __shfl_xor(s, off, 64);
            qq += __shfl_xor(qq, off, 64);
        }
        if (lane == 0) { sred[wv * 2] = s; sred[wv * 2 + 1] = qq; }
    }
    __syncthreads();
    float S = sred[0] + sred[2] + sred[4] + sred[6];
    float Q = sred[1] + sred[3] + sred[5] + sred[7];
    const float M = (float)NN * (float)HID;
    float mean = S / M;
    float rstd = rsqrtf(fmaxf(Q / M - mean * mean, 0.f) + LN_EPS);

    bf16x8 bfrag[2][4];
    #pragma unroll
    for (int ks = 0; ks < 4; ks++) {
        #pragma unroll
        for (int cc = 0; cc < 2; cc++) {
            int ct = wv * 2 + cc;
            uint4 r = *(const uint4*)&wb[(size_t)((ks * 9 + ct) * 64 + lane) * 4];
            bfrag[cc][ks] = __builtin_bit_cast(bf16x8, r);
        }
    }
    bf16x8 bal[4];
    #pragma unroll
    for (int ks = 0; ks < 4; ks++) {
        uint4 r = *(const uint4*)&wb[(size_t)((ks * 9 + 8) * 64 + lane) * 4];
        bal[ks] = __builtin_bit_cast(bf16x8, r);
    }

    {
        int row = t >> 2;
        int qq = t & 3;
        int gr = n0 + row;
        int rt = row >> 4, m = row & 15;
        #pragma unroll
        for (int ks = 0; ks < 4; ks++) {
            int kk = ks * 32 + qq * 8;
            uint4 op = make_uint4(0u, 0u, 0u, 0u);
            if (gr < NN) {
                size_t base = (size_t)gr * HQ + (kk >> 1);
                uint4 gp = *(const uint4*)&g[base];
                uint4 hp = *(const uint4*)&h[base];
                float4 wA = *(const float4*)&lnw[kk];
                float4 wB = *(const float4*)&lnw[kk + 4];
                float4 bA = *(const float4*)&lnb[kk];
                float4 bB = *(const float4*)&lnb[kk + 4];
                float v0 = fmaxf((bflo(gp.x) - mean) * rstd * wA.x + bA.x + bflo(hp.x), 0.f);
                float v1 = fmaxf((bfhi(gp.x) - mean) * rstd * wA.y + bA.y + bfhi(hp.x), 0.f);
                float v2 = fmaxf((bflo(gp.y) - mean) * rstd * wA.z + bA.z + bflo(hp.y), 0.f);
                float v3 = fmaxf((bfhi(gp.y) - mean) * rstd * wA.w + bA.w + bfhi(hp.y), 0.f);
                float v4 = fmaxf((bflo(gp.z) - mean) * rstd * wB.x + bB.x + bflo(hp.z), 0.f);
                float v5 = fmaxf((bfhi(gp.z) - mean) * rstd * wB.y + bB.y + bfhi(hp.z), 0.f);
                float v6 = fmaxf((bflo(gp.w) - mean) * rstd * wB.z + bB.z + bflo(hp.w), 0.f);
                float v7 = fmaxf((bfhi(gp.w) - mean) * rstd * wB.w + bB.w + bfhi(hp.w), 0.f);
                op.x = pack2(v0, v1); op.y = pack2(v2, v3);
                op.z = pack2(v4, v5); op.w = pack2(v6, v7);
                *(uint4*)&hout[base] = op;
            }
            *(uint4*)&hsu[((rt * 4 + ks) * 64 + qq * 16 + m) * 4] = op;
        }
    }
    __syncthreads();

    f32x4 acc[4][2];
    f32x4 accal[4];
    #pragma unroll
    for (int rt = 0; rt < 4; rt++) {
        acc[rt][0] = (f32x4){0.f, 0.f, 0.f, 0.f};
        acc[rt][1] = (f32x4){0.f, 0.f, 0.f, 0.f};
        accal[rt]  = (f32x4){0.f, 0.f, 0.f, 0.f};
    }
    #pragma unroll
    for (int rt = 0; rt < 4; rt++) {
        #pragma unroll
        for (int ks = 0; ks < 4; ks++) {
            uint4 araw = *(const uint4*)&hsu[((rt * 4 + ks) * 64 + lane) * 4];
            bf16x8 af = __builtin_bit_cast(bf16x8, araw);
            acc[rt][0] = __builtin_amdgcn_mfma_f32_16x16x32_bf16(af, bfrag[0][ks], acc[rt][0], 0, 0, 0);
            acc[rt][1] = __builtin_amdgcn_mfma_f32_16x16x32_bf16(af, bfrag[1][ks], acc[rt][1], 0, 0, 0);
            if (wv == 3)
                accal[rt] = __builtin_amdgcn_mfma_f32_16x16x32_bf16(af, bal[ks], accal[rt], 0, 0, 0);
        }
    }

    #pragma unroll
    for (int rt = 0; rt < 4; rt++) {
        #pragma unroll
        for (int reg = 0; reg < 4; reg++) {
            int row = n0 + rt * 16 + q * 4 + reg;
            #pragma unroll
            for (int cc = 0; cc < 2; cc++) {
                float v = acc[rt][cc][reg];
                float vp = __shfl_xor(v, 1, 64);
                if (!(n16 & 1) && row < NN) {
                    int colp = (wv * 2 + cc) * 8 + (n16 >> 1);
                    xh[(size_t)row * HQ + colp] = pack2(v, vp);
                }
            }
            if (wv == 3 && row < NN && n16 < 8) {
                float v = accal[rt][reg];
                if (n16 < 4) al_s[row * 4 + n16] = v;
                else         al_d[row * 4 + (n16 - 4)] = v;
            }
        }
    }
}

// ---------------------------------------------------------------------------
// GAT aggregation v6 (bf16 xh): one wave = 8 consecutive nodes. Pass 2:
// 8 lanes/node x 16 channels (2 uint4 per edge), 2x unrolled. den redundant
// per node; synthetic self-loops; rowptr broadcast via shfl.
// ---------------------------------------------------------------------------
__global__ __launch_bounds__(256) void gat_agg_kernel(const int* __restrict__ rowptr,
        const uint2* __restrict__ edges, const u32* __restrict__ xh,
        const float* __restrict__ al_s, const float* __restrict__ al_d,
        const float* __restrict__ wedot, const float* __restrict__ bg,
        u32* __restrict__ g, float* __restrict__ partials) {
    __shared__ float lds_ex[4][GCAP * 4];
    __shared__ float lds_ea[4][GCAP];
    __shared__ int lds_src[4][GCAP];
    int wv = threadIdx.x >> 6, lane = threadIdx.x & 63;
    int base = (blockIdx.x * 4 + wv) * 8;
    if (base >= NN) return;
    float* ex_w = lds_ex[wv];
    float* ea_w = lds_ea[wv];
    int* src_w = lds_src[wv];
    int rv = 0;
    if (lane < 9) {
        int idx = base + lane;
        rv = rowptr[idx < NN ? idx : NN];
    }
    int r0 = __shfl(rv, 0, 64), r1 = __shfl(rv, 1, 64), r2 = __shfl(rv, 2, 64);
    int r3 = __shfl(rv, 3, 64), r4 = __shfl(rv, 4, 64), r5 = __shfl(rv, 5, 64);
    int r6 = __shfl(rv, 6, 64), r7 = __shfl(rv, 7, 64), r8 = __shfl(rv, 8, 64);
    int span = r8 - r0;
    int ncached = span < GCAP ? span : GCAP;
    float wd0 = wedot[0], wd1 = wedot[1], wd2 = wedot[2], wd3 = wedot[3];

    for (int i = lane; i < ncached; i += 64) {
        int gi = r0 + i;
        uint2 e = edges[gi];
        int s = (int)e.x;
        float eav = __uint_as_float(e.y);
        int d = (gi >= r1) + (gi >= r2) + (gi >= r3) + (gi >= r4)
              + (gi >= r5) + (gi >= r6) + (gi >= r7);
        float4 aldv = *(const float4*)&al_d[(base + d) * 4];
        float4 als = *(const float4*)&al_s[s * 4];
        float e0 = __expf(lrelu(als.x + aldv.x + eav * wd0));
        float e1 = __expf(lrelu(als.y + aldv.y + eav * wd1));
        float e2 = __expf(lrelu(als.z + aldv.z + eav * wd2));
        float e3 = __expf(lrelu(als.w + aldv.w + eav * wd3));
        src_w[i] = s;
        ea_w[i] = eav;
        *(float4*)&ex_w[i * 4] = make_float4(e0, e1, e2, e3);
    }
    // wave-private LDS rows; same-wave ops in order -> no barrier

    int nl = lane >> 3, cg = lane & 7;
    int n = base + nl;
    bool nvalid = n < NN;
    int lsv, lev;
    {
        int ra = nl == 0 ? r0 : nl == 1 ? r1 : nl == 2 ? r2 : nl == 3 ? r3
               : nl == 4 ? r4 : nl == 5 ? r5 : nl == 6 ? r6 : r7;
        int rb = nl == 0 ? r1 : nl == 1 ? r2 : nl == 2 ? r3 : nl == 3 ? r4
               : nl == 4 ? r5 : nl == 5 ? r6 : nl == 6 ? r7 : r8;
        lsv = ra - r0; lev = rb - r0;
    }
    int lec = lev < ncached ? lev : ncached;
    int head = cg >> 1;
    int c8 = cg * 8;                          // u32 offset of lane's 16 channels
    float wdh = head == 0 ? wd0 : head == 1 ? wd1 : head == 2 ? wd2 : wd3;
    float a0 = 0.f, a1 = 0.f, a2 = 0.f, a3 = 0.f;
    float a4 = 0.f, a5 = 0.f, a6 = 0.f, a7 = 0.f;
    float a8 = 0.f, a9 = 0.f, aA = 0.f, aB = 0.f;
    float aC = 0.f, aD = 0.f, aE = 0.f, aF = 0.f;
    float den = 0.f, easum = 0.f;
    int j = lsv;
    for (; j + 1 < lec; j += 2) {             // 4 uint4 loads in flight
        int s0 = src_w[j], s1 = src_w[j + 1];
        float e0 = ex_w[j * 4 + head], e1 = ex_w[(j + 1) * 4 + head];
        const u32* p0 = &xh[(size_t)s0 * HQ + c8];
        const u32* p1 = &xh[(size_t)s1 * HQ + c8];
        uint4 x0a = *(const uint4*)p0, x0b = *(const uint4*)(p0 + 4);
        uint4 x1a = *(const uint4*)p1, x1b = *(const uint4*)(p1 + 4);
        den += e0 + e1;
        easum += ea_w[j] + ea_w[j + 1];
        a0 += e0 * bflo(x0a.x); a1 += e0 * bfhi(x0a.x);
        a2 += e0 * bflo(x0a.y); a3 += e0 * bfhi(x0a.y);
        a4 += e0 * bflo(x0a.z); a5 += e0 * bfhi(x0a.z);
        a6 += e0 * bflo(x0a.w); a7 += e0 * bfhi(x0a.w);
        a8 += e0 * bflo(x0b.x); a9 += e0 * bfhi(x0b.x);
        aA += e0 * bflo(x0b.y); aB += e0 * bfhi(x0b.y);
        aC += e0 * bflo(x0b.z); aD += e0 * bfhi(x0b.z);
        aE += e0 * bflo(x0b.w); aF += e0 * bfhi(x0b.w);
        a0 += e1 * bflo(x1a.x); a1 += e1 * bfhi(x1a.x);
        a2 += e1 * bflo(x1a.y); a3 += e1 * bfhi(x1a.y);
        a4 += e1 * bflo(x1a.z); a5 += e1 * bfhi(x1a.z);
        a6 += e1 * bflo(x1a.w); a7 += e1 * bfhi(x1a.w);
        a8 += e1 * bflo(x1b.x); a9 += e1 * bfhi(x1b.x);
        aA += e1 * bflo(x1b.y); aB += e1 * bfhi(x1b.y);
        aC += e1 * bflo(x1b.z); aD += e1 * bfhi(x1b.z);
        aE += e1 * bflo(x1b.w); aF += e1 * bfhi(x1b.w);
    }
    if (j < lec) {
        int s0 = src_w[j];
        float e0 = ex_w[j * 4 + head];
        const u32* p0 = &xh[(size_t)s0 * HQ + c8];
        uint4 x0a = *(const uint4*)p0, x0b = *(const uint4*)(p0 + 4);
        den += e0;
        easum += ea_w[j];
        a0 += e0 * bflo(x0a.x); a1 += e0 * bfhi(x0a.x);
        a2 += e0 * bflo(x0a.y); a3 += e0 * bfhi(x0a.y);
        a4 += e0 * bflo(x0a.z); a5 += e0 * bfhi(x0a.z);
        a6 += e0 * bflo(x0a.w); a7 += e0 * bfhi(x0a.w);
        a8 += e0 * bflo(x0b.x); a9 += e0 * bfhi(x0b.x);
        aA += e0 * bflo(x0b.y); aB += e0 * bfhi(x0b.y);
        aC += e0 * bflo(x0b.z); aD += e0 * bfhi(x0b.z);
        aE += e0 * bflo(x0b.w); aF += e0 * bfhi(x0b.w);
        j++;
    }
    // tail beyond LDS cache (rare): recompute logits for this head
    if (lev > lec && nvalid) {
        float aldh = al_d[n * 4 + head];
        for (int jt = (lsv > lec ? lsv : lec); jt < lev; jt++) {
            uint2 e = edges[r0 + jt];
            int s = (int)e.x;
            float eav = __uint_as_float(e.y);
            float ex = __expf(lrelu(al_s[s * 4 + head] + aldh + eav * wdh));
            den += ex;
            easum += eav;
            const u32* p0 = &xh[(size_t)s * HQ + c8];
            uint4 x0a = *(const uint4*)p0, x0b = *(const uint4*)(p0 + 4);
            a0 += ex * bflo(x0a.x); a1 += ex * bfhi(x0a.x);
            a2 += ex * bflo(x0a.y); a3 += ex * bfhi(x0a.y);
            a4 += ex * bflo(x0a.z); a5 += ex * bfhi(x0a.z);
            a6 += ex * bflo(x0a.w); a7 += ex * bfhi(x0a.w);
            a8 += ex * bflo(x0b.x); a9 += ex * bfhi(x0b.x);
            aA += ex * bflo(x0b.y); aB += ex * bfhi(x0b.y);
            aC += ex * bflo(x0b.z); aD += ex * bfhi(x0b.z);
            aE += ex * bflo(x0b.w); aF += ex * bfhi(x0b.w);
        }
    }
    // synthetic self-loop: attr = mean of real edge attrs (PyG fill='mean')
    if (nvalid) {
        float mea = easum / fmaxf((float)(lev - lsv), 1.0f);
        float alh = al_s[n * 4 + head] + al_d[n * 4 + head];
        float ex = __expf(lrelu(alh + mea * wdh));
        den += ex;
        const u32* p0 = &xh[(size_t)n * HQ + c8];
        uint4 x0a = *(const uint4*)p0, x0b = *(const uint4*)(p0 + 4);
        a0 += ex * bflo(x0a.x); a1 += ex * bfhi(x0a.x);
        a2 += ex * bflo(x0a.y); a3 += ex * bfhi(x0a.y);
        a4 += ex * bflo(x0a.z); a5 += ex * bfhi(x0a.z);
        a6 += ex * bflo(x0a.w); a7 += ex * bfhi(x0a.w);
        a8 += ex * bflo(x0b.x); a9 += ex * bfhi(x0b.x);
        aA += ex * bflo(x0b.y); aB += ex * bfhi(x0b.y);
        aC += ex * bflo(x0b.z); aD += ex * bfhi(x0b.z);
        aE += ex * bflo(x0b.w); aF += ex * bfhi(x0b.w);
    }

    float inv = 1.0f / (den + 1e-16f);
    int c0 = cg * 16;
    float4 bg0 = *(const float4*)&bg[c0];
    float4 bg1 = *(const float4*)&bg[c0 + 4];
    float4 bg2 = *(const float4*)&bg[c0 + 8];
    float4 bg3 = *(const float4*)&bg[c0 + 12];
    float o0 = a0 * inv + bg0.x, o1 = a1 * inv + bg0.y;
    float o2 = a2 * inv + bg0.z, o3 = a3 * inv + bg0.w;
    float o4 = a4 * inv + bg1.x, o5 = a5 * inv + bg1.y;
    float o6 = a6 * inv + bg1.z, o7 = a7 * inv + bg1.w;
    float o8 = a8 * inv + bg2.x, o9 = a9 * inv + bg2.y;
    float oA = aA * inv + bg2.z, oB = aB * inv + bg2.w;
    float oC = aC * inv + bg3.x, oD = aD * inv + bg3.y;
    float oE = aE * inv + bg3.z, oF = aF * inv + bg3.w;
    float ss = 0.f, sq = 0.f;
    if (nvalid) {
        uint4 opA, opB;
        opA.x = pack2(o0, o1); opA.y = pack2(o2, o3);
        opA.z = pack2(o4, o5); opA.w = pack2(o6, o7);
        opB.x = pack2(o8, o9); opB.y = pack2(oA, oB);
        opB.z = pack2(oC, oD); opB.w = pack2(oE, oF);
        *(uint4*)&g[(size_t)n * HQ + c8] = opA;
        *(uint4*)&g[(size_t)n * HQ + c8 + 4] = opB;
        ss = o0 + o1 + o2 + o3 + o4 + o5 + o6 + o7
           + o8 + o9 + oA + oB + oC + oD + oE + oF;
        sq = o0 * o0 + o1 * o1 + o2 * o2 + o3 * o3
           + o4 * o4 + o5 * o5 + o6 * o6 + o7 * o7
           + o8 * o8 + o9 * o9 + oA * oA + oB * oB
           + oC * oC + oD * oD + oE * oE + oF * oF;
    }
    #pragma unroll
    for (int off = 1; off <= 32; off <<= 1) {
        ss += __shfl_xor(ss, off, 64);
        sq += __shfl_xor(sq, off, 64);
    }
    if (lane == 0) {
        int sl = ((blockIdx.x * 4 + wv) & 1023) * 2;
        atomicAdd(&partials[sl], ss);
        atomicAdd(&partials[sl + 1], sq);
    }
}

// final: out = relu(LN(g)+h) @ Wout + bout.  LN stats reduced inline.
__global__ __launch_bounds__(256) void ln_out_kernel(const u32* __restrict__ g,
        const u32* __restrict__ h, const float* __restrict__ lnw,
        const float* __restrict__ lnb, const float* __restrict__ partials,
        const float* __restrict__ Wout, const float* __restrict__ bout,
        float* __restrict__ out) {
    __shared__ float wsh[HID * NOUT];
    __shared__ float sred[8];
    int t = threadIdx.x;
    int wv = t >> 6, lane = t & 63;
    {
        const float4* pp = (const float4*)partials;
        float4 v0 = pp[t * 2], v1 = pp[t * 2 + 1];
        float s = v0.x + v0.z + v1.x + v1.z;
        float qq = v0.y + v0.w + v1.y + v1.w;
        #pragma unroll
        for (int off = 1; off <= 32; off <<= 1) {
            s += __shfl_xor(s, off, 64);
            qq += __shfl_xor(qq, off, 64);
        }
        if (lane == 0) { sred[wv * 2] = s; sred[wv * 2 + 1] = qq; }
    }
    for (int i = t; i < HID * NOUT; i += 256) wsh[i] = Wout[i];
    __syncthreads();
    float S = sred[0] + sred[2] + sred[4] + sred[6];
    float Q = sred[1] + sred[3] + sred[5] + sred[7];
    const float M = (float)NN * (float)HID;
    float mean = S / M;
    float rstd = rsqrtf(fmaxf(Q / M - mean * mean, 0.f) + LN_EPS);

    int nl = lane >> 4, cg = lane & 15;
    int n = (blockIdx.x * 4 + wv) * 4 + nl;
    bool nvalid = n < NN;
    float p[NOUT] = {};
    if (nvalid) {
        int c0 = cg * 8;
        uint4 gv = *(const uint4*)&g[(size_t)n * HQ + cg * 4];
        uint4 hv = *(const uint4*)&h[(size_t)n * HQ + cg * 4];
        float4 wA = *(const float4*)&lnw[c0], wB = *(const float4*)&lnw[c0 + 4];
        float4 bA = *(const float4*)&lnb[c0], bB = *(const float4*)&lnb[c0 + 4];
        float o[8];
        o[0] = fmaxf((bflo(gv.x) - mean) * rstd * wA.x + bA.x + bflo(hv.x), 0.f);
        o[1] = fmaxf((bfhi(gv.x) - mean) * rstd * wA.y + bA.y + bfhi(hv.x), 0.f);
        o[2] = fmaxf((bflo(gv.y) - mean) * rstd * wA.z + bA.z + bflo(hv.y), 0.f);
        o[3] = fmaxf((bfhi(gv.y) - mean) * rstd * wA.w + bA.w + bfhi(hv.y), 0.f);
        o[4] = fmaxf((bflo(gv.z) - mean) * rstd * wB.x + bB.x + bflo(hv.z), 0.f);
        o[5] = fmaxf((bfhi(gv.z) - mean) * rstd * wB.y + bB.y + bfhi(hv.z), 0.f);
        o[6] = fmaxf((bflo(gv.w) - mean) * rstd * wB.z + bB.z + bflo(hv.w), 0.f);
        o[7] = fmaxf((bfhi(gv.w) - mean) * rstd * wB.w + bB.w + bfhi(hv.w), 0.f);
        #pragma unroll
        for (int jj = 0; jj < NOUT; jj++) {
            float acc = 0.f;
            #pragma unroll
            for (int k = 0; k < 8; k++) acc += o[k] * wsh[(c0 + k) * NOUT + jj];
            p[jj] = acc;
        }
    }
    #pragma unroll
    for (int off = 1; off <= 8; off <<= 1) {
        #pragma unroll
        for (int jj = 0; jj < NOUT; jj++) p[jj] += __shfl_xor(p[jj], off, 64);
    }
    if (cg == 0 && nvalid) {
        #pragma unroll
        for (int jj = 0; jj < NOUT; jj++)
            out[(size_t)n * NOUT + jj] = p[jj] + bout[jj];
    }
}

// ---------------------------------------------------------------------------
extern "C" void kernel_launch(void* const* d_in, const int* in_sizes, int n_in,
                              void* d_out, int out_size, void* d_ws, size_t ws_size,
                              hipStream_t stream) {
    const float* x      = (const float*)d_in[0];
    const int*   ei     = (const int*)d_in[1];
    const float* ea     = (const float*)d_in[2];
    const float* Win    = (const float*)d_in[3];
    const float* b_in   = (const float*)d_in[4];
    const float* Wg     = (const float*)d_in[5];
    const float* bg     = (const float*)d_in[6];
    const float* a_src  = (const float*)d_in[7];
    const float* a_dst  = (const float*)d_in[8];
    const float* We     = (const float*)d_in[9];
    const float* a_edge = (const float*)d_in[10];
    const float* ln_w   = (const float*)d_in[11];
    const float* ln_b   = (const float*)d_in[12];
    const float* Wout   = (const float*)d_in[13];
    const float* bout   = (const float*)d_in[14];
    float* out = (float*)d_out;

    char* w = (char*)d_ws;
    size_t off = 0;
    auto alloc = [&](size_t bytes) -> void* {
        void* p = w + off;
        off = (off + bytes + 255) & ~(size_t)255;
        return p;
    };
    // zeroed region first (one memset): cnt + partials + scan state
    int*   cnt      = (int*)alloc(NN * sizeof(int));
    float* partials = (float*)alloc(3 * 2048 * sizeof(float));
    int*   sums     = (int*)alloc(NB_SCAN * sizeof(int));
    int*   prefixes = (int*)alloc(NB_SCAN * sizeof(int));
    int*   flags    = (int*)alloc(NB_SCAN * sizeof(int));
    size_t zero_span = off;
    u32*   slot    = (u32*)alloc((size_t)EE * sizeof(u32));
    int*   rowptr  = (int*)alloc((NN + 1) * sizeof(int));
    uint2* edges   = (uint2*)alloc((size_t)EE * sizeof(uint2));
    u32*   h       = (u32*)alloc((size_t)NN * HQ * sizeof(u32));
    u32*   g       = (u32*)alloc((size_t)NN * HQ * sizeof(u32));
    u32*   xh      = (u32*)alloc((size_t)NN * HQ * sizeof(u32));
    float* al_s    = (float*)alloc((size_t)NN * NH * sizeof(float));
    float* al_d    = (float*)alloc((size_t)NN * NH * sizeof(float));
    float* wedot   = (float*)alloc(16 * sizeof(float));
    float* wf      = (float*)alloc(34 * HID * sizeof(float));
    float* wga     = (float*)alloc(HID * 8 * sizeof(float));
    u32*   wb      = (u32*)alloc((size_t)2 * WB_LSZ * sizeof(u32));
    u32*   wb2     = (u32*)alloc(17 * 64 * 4 * sizeof(u32));
    (void)ws_size; (void)n_in; (void)in_sizes; (void)out_size;

    hipMemsetAsync(d_ws, 0, zero_span, stream);
    // A: hist (16 edges/thread) || weight prep
    hist_prep_kernel<<<HB16 + 36, 256, 0, stream>>>(ei, cnt, slot, We, a_edge, wedot,
                                                    Win, b_in, Wg, wf, a_src, a_dst,
                                                    wb, wga);
    // B: single-pass scan (decoupled lookback) || prep2
    scan_prep2_kernel<<<NB_SCAN + 18, 1024, 0, stream>>>(cnt, rowptr, sums, prefixes,
                                                         flags, Win, b_in, wga, wf, wb2);
    // C: scatter (16 edges/thread) || layer-0 MFMA GEMM
    scatter_ingemm_kernel<<<SB16 + NG64, 256, 0, stream>>>(ei, ea, rowptr, slot, edges,
                                                           x, wb2, wf, b_in, h, xh,
                                                           al_s, al_d);
    for (int l = 0; l < NL; l++) {
        if (l > 0) {
            gemm_mfma_kernel<<<NG64, 256, 0, stream>>>(
                h, wb + (size_t)(l - 1) * WB_LSZ, xh, g,
                ln_w + (size_t)(l - 1) * HID, ln_b + (size_t)(l - 1) * HID,
                partials + (size_t)(l - 1) * 2048, h, al_s, al_d);
        }
        gat_agg_kernel<<<(NN + 31) / 32, 256, 0, stream>>>(
            rowptr, edges, xh, al_s, al_d, wedot + l * 4,
            bg + (size_t)l * HID, g, partials + (size_t)l * 2048);
    }

    ln_out_kernel<<<(NN + 15) / 16, 256, 0, stream>>>(g, h, ln_w + (size_t)2 * HID,
                                                      ln_b + (size_t)2 * HID,
                                                      partials + 2 * 2048, Wout, bout, out);
}

// Round 17
// 377.193 us; speedup vs baseline: 1.0525x; 1.0525x over previous
//
#include <hip/hip_runtime.h>
#include <hip/hip_bf16.h>

#define NN 100000
#define EE 800000
#define HID 128
#define NH 4
#define CH 32
#define NL 3
#define NOUT 5
#define NEG_SLOPE 0.2f
#define LN_EPS 1e-5f
#define GCAP 128           // LDS-cached edges per 8-node wave group (real edges only)
#define NB_SCAN 98         // ceil((NN+1)/1024)
#define HQ (HID / 2)       // u32-packed bf16 pairs per row
#define WB_LSZ 9216        // u32 per layer of packed B-frags: 4ks*9ct*64lane*4
#define HB8 391            // hist blocks: ceil(EE/2048), 8 edges/thread
#define SB8 391            // scatter blocks, 8 edges/thread
#define NG64 1563          // in_gemm blocks = ceil(NN/64)

typedef unsigned int u32;
typedef __attribute__((ext_vector_type(8))) short bf16x8;
typedef __attribute__((ext_vector_type(4))) float f32x4;

static __device__ __forceinline__ float bflo(u32 r) { return __uint_as_float(r << 16); }
static __device__ __forceinline__ float bfhi(u32 r) { return __uint_as_float(r & 0xffff0000u); }
static __device__ __forceinline__ unsigned short f2bf(float x) {
    union U { __hip_bfloat16 b; unsigned short s; } u;
    u.b = __float2bfloat16(x);
    return u.s;
}
static __device__ __forceinline__ u32 pack2(float a, float b) {
    return (u32)f2bf(a) | ((u32)f2bf(b) << 16);
}
static __device__ __forceinline__ float lrelu(float x) {
    return x > 0.f ? x : NEG_SLOPE * x;
}

// ---------------------------------------------------------------------------
// Fused dispatch A: hist (blocks 0..HB8-1, 8 edges/thread) || weight prep.
// ---------------------------------------------------------------------------
__global__ void hist_prep_kernel(const int* __restrict__ ei, int* __restrict__ cnt,
                                 u32* __restrict__ slot,
                                 const float* __restrict__ We, const float* __restrict__ a_e,
                                 float* __restrict__ wedot,
                                 const float* __restrict__ Win, const float* __restrict__ b_in,
                                 const float* __restrict__ Wg, float* __restrict__ wf,
                                 const float* __restrict__ a_src, const float* __restrict__ a_dst,
                                 u32* __restrict__ wb, float* __restrict__ wga) {
    int b = blockIdx.x, t = threadIdx.x;
    if (b < HB8) {
        int e0 = b * 2048 + t;
        #pragma unroll
        for (int k = 0; k < 8; k++) {
            int e = e0 + k * 256;
            if (e < EE) {
                int d = ei[EE + e];
                int s = atomicAdd(&cnt[d], 1);
                slot[e] = ((u32)d << 8) | (u32)s;
            }
        }
        return;
    }
    if (b == HB8) {
        if (t < NL * NH) {
            int l = t >> 2, hh = t & 3;
            float s = 0.f;
            #pragma unroll
            for (int c = 0; c < CH; c++)
                s += We[l * HID + hh * CH + c] * a_e[l * HID + hh * CH + c];
            wedot[t] = s;
        }
        // WgA0[m][j] = head-masked (Wg0 @ Aext): j<4 src head j, j>=4 dst head j-4
        for (int i = t; i < HID * 8; i += 256) {
            int m = i >> 3, j = i & 7;
            int hh = j & 3;
            const float* a = (j < 4) ? (a_src + hh * CH) : (a_dst + hh * CH);
            const float* wrow = Wg + (size_t)m * HID + hh * CH;
            float s = 0.f;
            #pragma unroll
            for (int c = 0; c < CH; c++) s += wrow[c] * a[c];
            wga[i] = s;
        }
        return;
    }
    if (b < HB8 + 18) {
        // wfuse: wf[r][c] = sum_k (r<32 ? Win[r][k] : b_in[k]) * Wg0[k][c]
        int idx = (b - HB8 - 1) * 256 + t;
        if (idx >= 33 * HID) return;
        int r = idx >> 7, c = idx & 127;
        float acc = 0.f;
        for (int k = 0; k < HID; k++) {
            float a = (r < 32) ? Win[r * HID + k] : b_in[k];
            acc += a * Wg[(size_t)k * HID + c];
        }
        wf[r * HID + c] = acc;
        return;
    }
    // pack Wg[1..2] (+ head-masked al columns as 9th col-tile) into B-frags
    {
        int idx = (b - HB8 - 18) * 256 + t;   // 0..4607
        if (idx >= 2 * 2304) return;
        int l = idx / 2304;
        int rem = idx % 2304;
        int ks = rem / 576;
        int ct = (rem % 576) / 64;
        int lane = rem % 64;
        int q = lane >> 4, n = lane & 15;
        const float* W = Wg + (size_t)(l + 1) * HID * HID;
        float v[8];
        if (ct < 8) {
            #pragma unroll
            for (int j = 0; j < 8; j++) {
                int k = ks * 32 + q * 8 + j;
                v[j] = W[(size_t)k * HID + ct * 16 + n];
            }
        } else {
            #pragma unroll
            for (int j = 0; j < 8; j++) v[j] = 0.f;
            if (n < 8) {
                const float* a = (n < 4) ? (a_src + (l + 1) * HID + (n & 3) * CH)
                                         : (a_dst + (l + 1) * HID + (n & 3) * CH);
                #pragma unroll
                for (int j = 0; j < 8; j++) {
                    int k = ks * 32 + q * 8 + j;
                    const float* wrow = W + (size_t)k * HID + (n & 3) * CH;
                    float s = 0.f;
                    for (int c = 0; c < CH; c++) s += wrow[c] * a[c];
                    v[j] = s;
                }
            }
        }
        u32* dst = wb + (size_t)l * WB_LSZ + (size_t)((ks * 9 + ct) * 64 + lane) * 4;
        dst[0] = pack2(v[0], v[1]); dst[1] = pack2(v[2], v[3]);
        dst[2] = pack2(v[4], v[5]); dst[3] = pack2(v[6], v[7]);
    }
}

// ---------------------------------------------------------------------------
// Fused dispatch B: single-pass scan (decoupled lookback) || prep2.
// ---------------------------------------------------------------------------
__global__ __launch_bounds__(1024) void scan_prep2_kernel(const int* __restrict__ cnt,
        int* __restrict__ rowptr, int* __restrict__ sums, int* __restrict__ prefixes,
        int* __restrict__ flags,
        const float* __restrict__ Win, const float* __restrict__ b_in,
        const float* __restrict__ wga, float* __restrict__ wf, u32* __restrict__ wb2) {
    if (blockIdx.x >= NB_SCAN) {
        int b = blockIdx.x - NB_SCAN;        // 0..17
        int lane = threadIdx.x;
        if (lane >= 64) return;
        int q = lane >> 4, n = lane & 15;
        if (b == 17) {
            if (lane < 8) {
                float s = 0.f;
                for (int m = 0; m < HID; m++) s += b_in[m] * wga[m * 8 + lane];
                wf[33 * HID + lane] = s;     // bfA
            }
            return;
        }
        float v[8];
        if (b < 8) {
            #pragma unroll
            for (int j = 0; j < 8; j++) v[j] = Win[(q * 8 + j) * HID + b * 16 + n];
        } else if (b < 16) {
            int ct = b - 8;
            #pragma unroll
            for (int j = 0; j < 8; j++) v[j] = wf[(q * 8 + j) * HID + ct * 16 + n];
        } else {                             // al tile: Win @ WgA0
            #pragma unroll
            for (int j = 0; j < 8; j++) v[j] = 0.f;
            if (n < 8) {
                #pragma unroll
                for (int j = 0; j < 8; j++) {
                    const float* wrow = Win + (q * 8 + j) * HID;
                    float s = 0.f;
                    for (int m = 0; m < HID; m++) s += wrow[m] * wga[m * 8 + n];
                    v[j] = s;
                }
            }
        }
        u32* dst = wb2 + (size_t)(b * 64 + lane) * 4;
        dst[0] = pack2(v[0], v[1]); dst[1] = pack2(v[2], v[3]);
        dst[2] = pack2(v[4], v[5]); dst[3] = pack2(v[6], v[7]);
        return;
    }
    // --- scan block ---
    __shared__ int ws[16];
    __shared__ int bprefix;
    int b = blockIdx.x;
    int gid = b * 1024 + threadIdx.x;
    int v = (gid < NN) ? cnt[gid] : 0;
    int lane = threadIdx.x & 63, wid = threadIdx.x >> 6;
    int s = v;
    #pragma unroll
    for (int off = 1; off < 64; off <<= 1) {
        int t2 = __shfl_up(s, off, 64);
        if (lane >= off) s += t2;
    }
    if (lane == 63) ws[wid] = s;
    __syncthreads();
    int add = 0;
    for (int w2 = 0; w2 < wid; w2++) add += ws[w2];
    int incl = s + add;                      // block-local inclusive
    if (threadIdx.x == 0) {
        int total = 0;
        for (int w2 = 0; w2 < 16; w2++) total += ws[w2];
        atomicExch(&sums[b], total);
        __threadfence();
        atomicExch(&flags[b], 1);
        int pfx = 0;
        for (int i = b - 1; i >= 0; i--) {
            int f;
            do { f = atomicAdd(&flags[i], 0); } while (f == 0);
            if (f == 2) { pfx += atomicAdd(&prefixes[i], 0); break; }
            pfx += atomicAdd(&sums[i], 0);
        }
        atomicExch(&prefixes[b], pfx + total);
        __threadfence();
        atomicExch(&flags[b], 2);
        bprefix = pfx;
    }
    __syncthreads();
    int pfx = bprefix;
    if (gid <= NN) rowptr[gid] = pfx + incl - v;   // exclusive
}

// ---------------------------------------------------------------------------
// Fused dispatch C: scatter (blocks 0..SB8-1, 8 edges/thread) || layer-0
// MFMA GEMM. xh stored bf16 (u32-packed).
// ---------------------------------------------------------------------------
__global__ __launch_bounds__(256) void scatter_ingemm_kernel(
        const int* __restrict__ ei, const float* __restrict__ ea,
        const int* __restrict__ rowptr, const u32* __restrict__ slot,
        uint2* __restrict__ edges,
        const float* __restrict__ x, const u32* __restrict__ wb2,
        const float* __restrict__ wf, const float* __restrict__ b_in,
        u32* __restrict__ h, u32* __restrict__ xh,
        float* __restrict__ al_s, float* __restrict__ al_d) {
    __shared__ u32 xsu[1024];                // used by the in_gemm branch only
    if (blockIdx.x < SB8) {
        int e0 = blockIdx.x * 2048 + threadIdx.x;
        #pragma unroll
        for (int k = 0; k < 8; k++) {
            int e = e0 + k * 256;
            if (e < EE) {
                u32 p = slot[e];
                int d = (int)(p >> 8);
                int pos = rowptr[d] + (int)(p & 255u);
                edges[pos] = make_uint2((u32)ei[e], __float_as_uint(ea[e]));
            }
        }
        return;
    }
    int t = threadIdx.x;
    int wv = t >> 6, lane = t & 63;
    int q = lane >> 4, n16 = lane & 15;
    int n0 = (blockIdx.x - SB8) * 64;
    // stage x -> bf16 A-frags
    {
        int row = t >> 2, qq = t & 3;
        int gr = n0 + row;
        int rt = row >> 4, m = row & 15;
        uint4 op = make_uint4(0u, 0u, 0u, 0u);
        if (gr < NN) {
            float4 vA = *(const float4*)&x[(size_t)gr * 32 + qq * 8];
            float4 vB = *(const float4*)&x[(size_t)gr * 32 + qq * 8 + 4];
            op.x = pack2(vA.x, vA.y); op.y = pack2(vA.z, vA.w);
            op.z = pack2(vB.x, vB.y); op.w = pack2(vB.z, vB.w);
        }
        *(uint4*)&xsu[(rt * 64 + qq * 16 + m) * 4] = op;
    }
    bf16x8 bwin[2], bwf[2], bal;
    #pragma unroll
    for (int cc = 0; cc < 2; cc++) {
        uint4 r0 = *(const uint4*)&wb2[(size_t)(((wv * 2 + cc)) * 64 + lane) * 4];
        uint4 r1 = *(const uint4*)&wb2[(size_t)((8 + wv * 2 + cc) * 64 + lane) * 4];
        bwin[cc] = __builtin_bit_cast(bf16x8, r0);
        bwf[cc]  = __builtin_bit_cast(bf16x8, r1);
    }
    {
        uint4 r = *(const uint4*)&wb2[(size_t)(16 * 64 + lane) * 4];
        bal = __builtin_bit_cast(bf16x8, r);
    }
    __syncthreads();
    f32x4 acch[4][2], accx[4][2], accal[4];
    #pragma unroll
    for (int rt = 0; rt < 4; rt++) {
        acch[rt][0] = (f32x4){0.f, 0.f, 0.f, 0.f};
        acch[rt][1] = (f32x4){0.f, 0.f, 0.f, 0.f};
        accx[rt][0] = (f32x4){0.f, 0.f, 0.f, 0.f};
        accx[rt][1] = (f32x4){0.f, 0.f, 0.f, 0.f};
        accal[rt]   = (f32x4){0.f, 0.f, 0.f, 0.f};
    }
    #pragma unroll
    for (int rt = 0; rt < 4; rt++) {
        uint4 araw = *(const uint4*)&xsu[(rt * 64 + lane) * 4];
        bf16x8 af = __builtin_bit_cast(bf16x8, araw);
        acch[rt][0] = __builtin_amdgcn_mfma_f32_16x16x32_bf16(af, bwin[0], acch[rt][0], 0, 0, 0);
        acch[rt][1] = __builtin_amdgcn_mfma_f32_16x16x32_bf16(af, bwin[1], acch[rt][1], 0, 0, 0);
        accx[rt][0] = __builtin_amdgcn_mfma_f32_16x16x32_bf16(af, bwf[0], accx[rt][0], 0, 0, 0);
        accx[rt][1] = __builtin_amdgcn_mfma_f32_16x16x32_bf16(af, bwf[1], accx[rt][1], 0, 0, 0);
        if (wv == 3)
            accal[rt] = __builtin_amdgcn_mfma_f32_16x16x32_bf16(af, bal, accal[rt], 0, 0, 0);
    }
    float bi[2], bfv[2];
    #pragma unroll
    for (int cc = 0; cc < 2; cc++) {
        int col = (wv * 2 + cc) * 16 + n16;
        bi[cc] = b_in[col];
        bfv[cc] = wf[32 * HID + col];
    }
    float bfa = (wv == 3 && n16 < 8) ? wf[33 * HID + n16] : 0.f;
    #pragma unroll
    for (int rt = 0; rt < 4; rt++) {
        #pragma unroll
        for (int reg = 0; reg < 4; reg++) {
            int row = n0 + rt * 16 + q * 4 + reg;
            #pragma unroll
            for (int cc = 0; cc < 2; cc++) {
                float v = acch[rt][cc][reg] + bi[cc];
                float vp = __shfl_xor(v, 1, 64);
                float u = accx[rt][cc][reg] + bfv[cc];
                float up = __shfl_xor(u, 1, 64);
                if (!(n16 & 1) && row < NN) {
                    int colp = (wv * 2 + cc) * 8 + (n16 >> 1);
                    h[(size_t)row * HQ + colp] = pack2(v, vp);
                    xh[(size_t)row * HQ + colp] = pack2(u, up);
                }
            }
            if (wv == 3 && row < NN && n16 < 8) {
                float v = accal[rt][reg] + bfa;
                if (n16 < 4) al_s[row * 4 + n16] = v;
                else         al_d[row * 4 + (n16 - 4)] = v;
            }
        }
    }
}

// ---------------------------------------------------------------------------
// Layers 1..2 via MFMA; LN stats inline; g/h staging loads hoisted upfront
// (8 uint4 in flight per thread during the latency-bound phase).
// ---------------------------------------------------------------------------
__global__ __launch_bounds__(256) void gemm_mfma_kernel(const u32* __restrict__ h,
        const u32* __restrict__ wb, u32* __restrict__ xh, const u32* __restrict__ g,
        const float* __restrict__ lnw, const float* __restrict__ lnb,
        const float* __restrict__ partials, u32* __restrict__ hout,
        float* __restrict__ al_s, float* __restrict__ al_d) {
    __shared__ u32 hsu[4096];                // 16KB, frag-ordered [rt][ks][lane][4]
    __shared__ float sred[8];
    int n0 = blockIdx.x * 64;
    int t = threadIdx.x;
    int wv = t >> 6, lane = t & 63;
    int q = lane >> 4, n16 = lane & 15;

    // issue all g/h staging loads FIRST (latency-bound phase: 8 loads in flight)
    int srow = t >> 2;
    int sqq = t & 3;
    int sgr = n0 + srow;
    int srt = srow >> 4, sm = srow & 15;
    bool svalid = sgr < NN;
    size_t sbase = (size_t)(svalid ? sgr : 0) * HQ + sqq * 4;
    uint4 gp[4], hp[4];
    #pragma unroll
    for (int ks = 0; ks < 4; ks++) {
        gp[ks] = *(const uint4*)&g[sbase + ks * 16];
        hp[ks] = *(const uint4*)&h[sbase + ks * 16];
    }

    {
        const float4* pp = (const float4*)partials;
        float4 v0 = pp[t * 2], v1 = pp[t * 2 + 1];
        float s = v0.x + v0.z + v1.x + v1.z;
        float qq = v0.y + v0.w + v1.y + v1.w;
        #pragma unroll
        for (int off = 1; off <= 32; off <<= 1) {
            s += __shfl_xor(s, off, 64);
            qq += __shfl_xor(qq, off, 64);
        }
        if (lane == 0) { sred[wv * 2] = s; sred[wv * 2 + 1] = qq; }
    }
    __syncthreads();
    float S = sred[0] + sred[2] + sred[4] + sred[6];
    float Q = sred[1] + sred[3] + sred[5] + sred[7];
    const float M = (float)NN * (float)HID;
    float mean = S / M;
    float rstd = rsqrtf(fmaxf(Q / M - mean * mean, 0.f) + LN_EPS);

    bf16x8 bfrag[2][4];
    #pragma unroll
    for (int ks = 0; ks < 4; ks++) {
        #pragma unroll
        for (int cc = 0; cc < 2; cc++) {
            int ct = wv * 2 + cc;
            uint4 r = *(const uint4*)&wb[(size_t)((ks * 9 + ct) * 64 + lane) * 4];
            bfrag[cc][ks] = __builtin_bit_cast(bf16x8, r);
        }
    }
    bf16x8 bal[4];
    #pragma unroll
    for (int ks = 0; ks < 4; ks++) {
        uint4 r = *(const uint4*)&wb[(size_t)((ks * 9 + 8) * 64 + lane) * 4];
        bal[ks] = __builtin_bit_cast(bf16x8, r);
    }

    // LN + relu + residual; write hout + LDS A-frags
    #pragma unroll
    for (int ks = 0; ks < 4; ks++) {
        int kk = ks * 32 + sqq * 8;
        uint4 op = make_uint4(0u, 0u, 0u, 0u);
        if (svalid) {
            float4 wA = *(const float4*)&lnw[kk];
            float4 wB = *(const float4*)&lnw[kk + 4];
            float4 bA = *(const float4*)&lnb[kk];
            float4 bB = *(const float4*)&lnb[kk + 4];
            float v0 = fmaxf((bflo(gp[ks].x) - mean) * rstd * wA.x + bA.x + bflo(hp[ks].x), 0.f);
            float v1 = fmaxf((bfhi(gp[ks].x) - mean) * rstd * wA.y + bA.y + bfhi(hp[ks].x), 0.f);
            float v2 = fmaxf((bflo(gp[ks].y) - mean) * rstd * wA.z + bA.z + bflo(hp[ks].y), 0.f);
            float v3 = fmaxf((bfhi(gp[ks].y) - mean) * rstd * wA.w + bA.w + bfhi(hp[ks].y), 0.f);
            float v4 = fmaxf((bflo(gp[ks].z) - mean) * rstd * wB.x + bB.x + bflo(hp[ks].z), 0.f);
            float v5 = fmaxf((bfhi(gp[ks].z) - mean) * rstd * wB.y + bB.y + bfhi(hp[ks].z), 0.f);
            float v6 = fmaxf((bflo(gp[ks].w) - mean) * rstd * wB.z + bB.z + bflo(hp[ks].w), 0.f);
            float v7 = fmaxf((bfhi(gp[ks].w) - mean) * rstd * wB.w + bB.w + bfhi(hp[ks].w), 0.f);
            op.x = pack2(v0, v1); op.y = pack2(v2, v3);
            op.z = pack2(v4, v5); op.w = pack2(v6, v7);
            *(uint4*)&hout[sbase + ks * 16] = op;
        }
        *(uint4*)&hsu[((srt * 4 + ks) * 64 + sqq * 16 + sm) * 4] = op;
    }
    __syncthreads();

    f32x4 acc[4][2];
    f32x4 accal[4];
    #pragma unroll
    for (int rt = 0; rt < 4; rt++) {
        acc[rt][0] = (f32x4){0.f, 0.f, 0.f, 0.f};
        acc[rt][1] = (f32x4){0.f, 0.f, 0.f, 0.f};
        accal[rt]  = (f32x4){0.f, 0.f, 0.f, 0.f};
    }
    #pragma unroll
    for (int rt = 0; rt < 4; rt++) {
        #pragma unroll
        for (int ks = 0; ks < 4; ks++) {
            uint4 araw = *(const uint4*)&hsu[((rt * 4 + ks) * 64 + lane) * 4];
            bf16x8 af = __builtin_bit_cast(bf16x8, araw);
            acc[rt][0] = __builtin_amdgcn_mfma_f32_16x16x32_bf16(af, bfrag[0][ks], acc[rt][0], 0, 0, 0);
            acc[rt][1] = __builtin_amdgcn_mfma_f32_16x16x32_bf16(af, bfrag[1][ks], acc[rt][1], 0, 0, 0);
            if (wv == 3)
                accal[rt] = __builtin_amdgcn_mfma_f32_16x16x32_bf16(af, bal[ks], accal[rt], 0, 0, 0);
        }
    }

    #pragma unroll
    for (int rt = 0; rt < 4; rt++) {
        #pragma unroll
        for (int reg = 0; reg < 4; reg++) {
            int row = n0 + rt * 16 + q * 4 + reg;
            #pragma unroll
            for (int cc = 0; cc < 2; cc++) {
                float v = acc[rt][cc][reg];
                float vp = __shfl_xor(v, 1, 64);
                if (!(n16 & 1) && row < NN) {
                    int colp = (wv * 2 + cc) * 8 + (n16 >> 1);
                    xh[(size_t)row * HQ + colp] = pack2(v, vp);
                }
            }
            if (wv == 3 && row < NN && n16 < 8) {
                float v = accal[rt][reg];
                if (n16 < 4) al_s[row * 4 + n16] = v;
                else         al_d[row * 4 + (n16 - 4)] = v;
            }
        }
    }
}

// ---------------------------------------------------------------------------
// GAT aggregation v6 (bf16 xh): one wave = 8 consecutive nodes. Pass 2:
// 8 lanes/node x 16 channels (2 uint4 per edge), 2x unrolled. den redundant
// per node; synthetic self-loops; rowptr broadcast via shfl.
// ---------------------------------------------------------------------------
__global__ __launch_bounds__(256) void gat_agg_kernel(const int* __restrict__ rowptr,
        const uint2* __restrict__ edges, const u32* __restrict__ xh,
        const float* __restrict__ al_s, const float* __restrict__ al_d,
        const float* __restrict__ wedot, const float* __restrict__ bg,
        u32* __restrict__ g, float* __restrict__ partials) {
    __shared__ float lds_ex[4][GCAP * 4];
    __shared__ float lds_ea[4][GCAP];
    __shared__ int lds_src[4][GCAP];
    int wv = threadIdx.x >> 6, lane = threadIdx.x & 63;
    int base = (blockIdx.x * 4 + wv) * 8;
    if (base >= NN) return;
    float* ex_w = lds_ex[wv];
    float* ea_w = lds_ea[wv];
    int* src_w = lds_src[wv];
    int rv = 0;
    if (lane < 9) {
        int idx = base + lane;
        rv = rowptr[idx < NN ? idx : NN];
    }
    int r0 = __shfl(rv, 0, 64), r1 = __shfl(rv, 1, 64), r2 = __shfl(rv, 2, 64);
    int r3 = __shfl(rv, 3, 64), r4 = __shfl(rv, 4, 64), r5 = __shfl(rv, 5, 64);
    int r6 = __shfl(rv, 6, 64), r7 = __shfl(rv, 7, 64), r8 = __shfl(rv, 8, 64);
    int span = r8 - r0;
    int ncached = span < GCAP ? span : GCAP;
    float wd0 = wedot[0], wd1 = wedot[1], wd2 = wedot[2], wd3 = wedot[3];

    for (int i = lane; i < ncached; i += 64) {
        int gi = r0 + i;
        uint2 e = edges[gi];
        int s = (int)e.x;
        float eav = __uint_as_float(e.y);
        int d = (gi >= r1) + (gi >= r2) + (gi >= r3) + (gi >= r4)
              + (gi >= r5) + (gi >= r6) + (gi >= r7);
        float4 aldv = *(const float4*)&al_d[(base + d) * 4];
        float4 als = *(const float4*)&al_s[s * 4];
        float e0 = __expf(lrelu(als.x + aldv.x + eav * wd0));
        float e1 = __expf(lrelu(als.y + aldv.y + eav * wd1));
        float e2 = __expf(lrelu(als.z + aldv.z + eav * wd2));
        float e3 = __expf(lrelu(als.w + aldv.w + eav * wd3));
        src_w[i] = s;
        ea_w[i] = eav;
        *(float4*)&ex_w[i * 4] = make_float4(e0, e1, e2, e3);
    }
    // wave-private LDS rows; same-wave ops in order -> no barrier

    int nl = lane >> 3, cg = lane & 7;
    int n = base + nl;
    bool nvalid = n < NN;
    int lsv, lev;
    {
        int ra = nl == 0 ? r0 : nl == 1 ? r1 : nl == 2 ? r2 : nl == 3 ? r3
               : nl == 4 ? r4 : nl == 5 ? r5 : nl == 6 ? r6 : r7;
        int rb = nl == 0 ? r1 : nl == 1 ? r2 : nl == 2 ? r3 : nl == 3 ? r4
               : nl == 4 ? r5 : nl == 5 ? r6 : nl == 6 ? r7 : r8;
        lsv = ra - r0; lev = rb - r0;
    }
    int lec = lev < ncached ? lev : ncached;
    int head = cg >> 1;
    int c8 = cg * 8;                          // u32 offset of lane's 16 channels
    float wdh = head == 0 ? wd0 : head == 1 ? wd1 : head == 2 ? wd2 : wd3;
    float a0 = 0.f, a1 = 0.f, a2 = 0.f, a3 = 0.f;
    float a4 = 0.f, a5 = 0.f, a6 = 0.f, a7 = 0.f;
    float a8 = 0.f, a9 = 0.f, aA = 0.f, aB = 0.f;
    float aC = 0.f, aD = 0.f, aE = 0.f, aF = 0.f;
    float den = 0.f, easum = 0.f;
    int j = lsv;
    for (; j + 1 < lec; j += 2) {             // 4 uint4 loads in flight
        int s0 = src_w[j], s1 = src_w[j + 1];
        float e0 = ex_w[j * 4 + head], e1 = ex_w[(j + 1) * 4 + head];
        const u32* p0 = &xh[(size_t)s0 * HQ + c8];
        const u32* p1 = &xh[(size_t)s1 * HQ + c8];
        uint4 x0a = *(const uint4*)p0, x0b = *(const uint4*)(p0 + 4);
        uint4 x1a = *(const uint4*)p1, x1b = *(const uint4*)(p1 + 4);
        den += e0 + e1;
        easum += ea_w[j] + ea_w[j + 1];
        a0 += e0 * bflo(x0a.x); a1 += e0 * bfhi(x0a.x);
        a2 += e0 * bflo(x0a.y); a3 += e0 * bfhi(x0a.y);
        a4 += e0 * bflo(x0a.z); a5 += e0 * bfhi(x0a.z);
        a6 += e0 * bflo(x0a.w); a7 += e0 * bfhi(x0a.w);
        a8 += e0 * bflo(x0b.x); a9 += e0 * bfhi(x0b.x);
        aA += e0 * bflo(x0b.y); aB += e0 * bfhi(x0b.y);
        aC += e0 * bflo(x0b.z); aD += e0 * bfhi(x0b.z);
        aE += e0 * bflo(x0b.w); aF += e0 * bfhi(x0b.w);
        a0 += e1 * bflo(x1a.x); a1 += e1 * bfhi(x1a.x);
        a2 += e1 * bflo(x1a.y); a3 += e1 * bfhi(x1a.y);
        a4 += e1 * bflo(x1a.z); a5 += e1 * bfhi(x1a.z);
        a6 += e1 * bflo(x1a.w); a7 += e1 * bfhi(x1a.w);
        a8 += e1 * bflo(x1b.x); a9 += e1 * bfhi(x1b.x);
        aA += e1 * bflo(x1b.y); aB += e1 * bfhi(x1b.y);
        aC += e1 * bflo(x1b.z); aD += e1 * bfhi(x1b.z);
        aE += e1 * bflo(x1b.w); aF += e1 * bfhi(x1b.w);
    }
    if (j < lec) {
        int s0 = src_w[j];
        float e0 = ex_w[j * 4 + head];
        const u32* p0 = &xh[(size_t)s0 * HQ + c8];
        uint4 x0a = *(const uint4*)p0, x0b = *(const uint4*)(p0 + 4);
        den += e0;
        easum += ea_w[j];
        a0 += e0 * bflo(x0a.x); a1 += e0 * bfhi(x0a.x);
        a2 += e0 * bflo(x0a.y); a3 += e0 * bfhi(x0a.y);
        a4 += e0 * bflo(x0a.z); a5 += e0 * bfhi(x0a.z);
        a6 += e0 * bflo(x0a.w); a7 += e0 * bfhi(x0a.w);
        a8 += e0 * bflo(x0b.x); a9 += e0 * bfhi(x0b.x);
        aA += e0 * bflo(x0b.y); aB += e0 * bfhi(x0b.y);
        aC += e0 * bflo(x0b.z); aD += e0 * bfhi(x0b.z);
        aE += e0 * bflo(x0b.w); aF += e0 * bfhi(x0b.w);
        j++;
    }
    // tail beyond LDS cache (rare): recompute logits for this head
    if (lev > lec && nvalid) {
        float aldh = al_d[n * 4 + head];
        for (int jt = (lsv > lec ? lsv : lec); jt < lev; jt++) {
            uint2 e = edges[r0 + jt];
            int s = (int)e.x;
            float eav = __uint_as_float(e.y);
            float ex = __expf(lrelu(al_s[s * 4 + head] + aldh + eav * wdh));
            den += ex;
            easum += eav;
            const u32* p0 = &xh[(size_t)s * HQ + c8];
            uint4 x0a = *(const uint4*)p0, x0b = *(const uint4*)(p0 + 4);
            a0 += ex * bflo(x0a.x); a1 += ex * bfhi(x0a.x);
            a2 += ex * bflo(x0a.y); a3 += ex * bfhi(x0a.y);
            a4 += ex * bflo(x0a.z); a5 += ex * bfhi(x0a.z);
            a6 += ex * bflo(x0a.w); a7 += ex * bfhi(x0a.w);
            a8 += ex * bflo(x0b.x); a9 += ex * bfhi(x0b.x);
            aA += ex * bflo(x0b.y); aB += ex * bfhi(x0b.y);
            aC += ex * bflo(x0b.z); aD += ex * bfhi(x0b.z);
            aE += ex * bflo(x0b.w); aF += ex * bfhi(x0b.w);
        }
    }
    // synthetic self-loop: attr = mean of real edge attrs (PyG fill='mean')
    if (nvalid) {
        float mea = easum / fmaxf((float)(lev - lsv), 1.0f);
        float alh = al_s[n * 4 + head] + al_d[n * 4 + head];
        float ex = __expf(lrelu(alh + mea * wdh));
        den += ex;
        const u32* p0 = &xh[(size_t)n * HQ + c8];
        uint4 x0a = *(const uint4*)p0, x0b = *(const uint4*)(p0 + 4);
        a0 += ex * bflo(x0a.x); a1 += ex * bfhi(x0a.x);
        a2 += ex * bflo(x0a.y); a3 += ex * bfhi(x0a.y);
        a4 += ex * bflo(x0a.z); a5 += ex * bfhi(x0a.z);
        a6 += ex * bflo(x0a.w); a7 += ex * bfhi(x0a.w);
        a8 += ex * bflo(x0b.x); a9 += ex * bfhi(x0b.x);
        aA += ex * bflo(x0b.y); aB += ex * bfhi(x0b.y);
        aC += ex * bflo(x0b.z); aD += ex * bfhi(x0b.z);
        aE += ex * bflo(x0b.w); aF += ex * bfhi(x0b.w);
    }

    float inv = 1.0f / (den + 1e-16f);
    int c0 = cg * 16;
    float4 bg0 = *(const float4*)&bg[c0];
    float4 bg1 = *(const float4*)&bg[c0 + 4];
    float4 bg2 = *(const float4*)&bg[c0 + 8];
    float4 bg3 = *(const float4*)&bg[c0 + 12];
    float o0 = a0 * inv + bg0.x, o1 = a1 * inv + bg0.y;
    float o2 = a2 * inv + bg0.z, o3 = a3 * inv + bg0.w;
    float o4 = a4 * inv + bg1.x, o5 = a5 * inv + bg1.y;
    float o6 = a6 * inv + bg1.z, o7 = a7 * inv + bg1.w;
    float o8 = a8 * inv + bg2.x, o9 = a9 * inv + bg2.y;
    float oA = aA * inv + bg2.z, oB = aB * inv + bg2.w;
    float oC = aC * inv + bg3.x, oD = aD * inv + bg3.y;
    float oE = aE * inv + bg3.z, oF = aF * inv + bg3.w;
    float ss = 0.f, sq = 0.f;
    if (nvalid) {
        uint4 opA, opB;
        opA.x = pack2(o0, o1); opA.y = pack2(o2, o3);
        opA.z = pack2(o4, o5); opA.w = pack2(o6, o7);
        opB.x = pack2(o8, o9); opB.y = pack2(oA, oB);
        opB.z = pack2(oC, oD); opB.w = pack2(oE, oF);
        *(uint4*)&g[(size_t)n * HQ + c8] = opA;
        *(uint4*)&g[(size_t)n * HQ + c8 + 4] = opB;
        ss = o0 + o1 + o2 + o3 + o4 + o5 + o6 + o7
           + o8 + o9 + oA + oB + oC + oD + oE + oF;
        sq = o0 * o0 + o1 * o1 + o2 * o2 + o3 * o3
           + o4 * o4 + o5 * o5 + o6 * o6 + o7 * o7
           + o8 * o8 + o9 * o9 + oA * oA + oB * oB
           + oC * oC + oD * oD + oE * oE + oF * oF;
    }
    #pragma unroll
    for (int off = 1; off <= 32; off <<= 1) {
        ss += __shfl_xor(ss, off, 64);
        sq += __shfl_xor(sq, off, 64);
    }
    if (lane == 0) {
        int sl = ((blockIdx.x * 4 + wv) & 1023) * 2;
        atomicAdd(&partials[sl], ss);
        atomicAdd(&partials[sl + 1], sq);
    }
}

// final: out = relu(LN(g)+h) @ Wout + bout.  LN stats reduced inline.
__global__ __launch_bounds__(256) void ln_out_kernel(const u32* __restrict__ g,
        const u32* __restrict__ h, const float* __restrict__ lnw,
        const float* __restrict__ lnb, const float* __restrict__ partials,
        const float* __restrict__ Wout, const float* __restrict__ bout,
        float* __restrict__ out) {
    __shared__ float wsh[HID * NOUT];
    __shared__ float sred[8];
    int t = threadIdx.x;
    int wv = t >> 6, lane = t & 63;
    {
        const float4* pp = (const float4*)partials;
        float4 v0 = pp[t * 2], v1 = pp[t * 2 + 1];
        float s = v0.x + v0.z + v1.x + v1.z;
        float qq = v0.y + v0.w + v1.y + v1.w;
        #pragma unroll
        for (int off = 1; off <= 32; off <<= 1) {
            s += __shfl_xor(s, off, 64);
            qq += __shfl_xor(qq, off, 64);
        }
        if (lane == 0) { sred[wv * 2] = s; sred[wv * 2 + 1] = qq; }
    }
    for (int i = t; i < HID * NOUT; i += 256) wsh[i] = Wout[i];
    __syncthreads();
    float S = sred[0] + sred[2] + sred[4] + sred[6];
    float Q = sred[1] + sred[3] + sred[5] + sred[7];
    const float M = (float)NN * (float)HID;
    float mean = S / M;
    float rstd = rsqrtf(fmaxf(Q / M - mean * mean, 0.f) + LN_EPS);

    int nl = lane >> 4, cg = lane & 15;
    int n = (blockIdx.x * 4 + wv) * 4 + nl;
    bool nvalid = n < NN;
    float p[NOUT] = {};
    if (nvalid) {
        int c0 = cg * 8;
        uint4 gv = *(const uint4*)&g[(size_t)n * HQ + cg * 4];
        uint4 hv = *(const uint4*)&h[(size_t)n * HQ + cg * 4];
        float4 wA = *(const float4*)&lnw[c0], wB = *(const float4*)&lnw[c0 + 4];
        float4 bA = *(const float4*)&lnb[c0], bB = *(const float4*)&lnb[c0 + 4];
        float o[8];
        o[0] = fmaxf((bflo(gv.x) - mean) * rstd * wA.x + bA.x + bflo(hv.x), 0.f);
        o[1] = fmaxf((bfhi(gv.x) - mean) * rstd * wA.y + bA.y + bfhi(hv.x), 0.f);
        o[2] = fmaxf((bflo(gv.y) - mean) * rstd * wA.z + bA.z + bflo(hv.y), 0.f);
        o[3] = fmaxf((bfhi(gv.y) - mean) * rstd * wA.w + bA.w + bfhi(hv.y), 0.f);
        o[4] = fmaxf((bflo(gv.z) - mean) * rstd * wB.x + bB.x + bflo(hv.z), 0.f);
        o[5] = fmaxf((bfhi(gv.z) - mean) * rstd * wB.y + bB.y + bfhi(hv.z), 0.f);
        o[6] = fmaxf((bflo(gv.w) - mean) * rstd * wB.z + bB.z + bflo(hv.w), 0.f);
        o[7] = fmaxf((bfhi(gv.w) - mean) * rstd * wB.w + bB.w + bfhi(hv.w), 0.f);
        #pragma unroll
        for (int jj = 0; jj < NOUT; jj++) {
            float acc = 0.f;
            #pragma unroll
            for (int k = 0; k < 8; k++) acc += o[k] * wsh[(c0 + k) * NOUT + jj];
            p[jj] = acc;
        }
    }
    #pragma unroll
    for (int off = 1; off <= 8; off <<= 1) {
        #pragma unroll
        for (int jj = 0; jj < NOUT; jj++) p[jj] += __shfl_xor(p[jj], off, 64);
    }
    if (cg == 0 && nvalid) {
        #pragma unroll
        for (int jj = 0; jj < NOUT; jj++)
            out[(size_t)n * NOUT + jj] = p[jj] + bout[jj];
    }
}

// ---------------------------------------------------------------------------
extern "C" void kernel_launch(void* const* d_in, const int* in_sizes, int n_in,
                              void* d_out, int out_size, void* d_ws, size_t ws_size,
                              hipStream_t stream) {
    const float* x      = (const float*)d_in[0];
    const int*   ei     = (const int*)d_in[1];
    const float* ea     = (const float*)d_in[2];
    const float* Win    = (const float*)d_in[3];
    const float* b_in   = (const float*)d_in[4];
    const float* Wg     = (const float*)d_in[5];
    const float* bg     = (const float*)d_in[6];
    const float* a_src  = (const float*)d_in[7];
    const float* a_dst  = (const float*)d_in[8];
    const float* We     = (const float*)d_in[9];
    const float* a_edge = (const float*)d_in[10];
    const float* ln_w   = (const float*)d_in[11];
    const float* ln_b   = (const float*)d_in[12];
    const float* Wout   = (const float*)d_in[13];
    const float* bout   = (const float*)d_in[14];
    float* out = (float*)d_out;

    char* w = (char*)d_ws;
    size_t off = 0;
    auto alloc = [&](size_t bytes) -> void* {
        void* p = w + off;
        off = (off + bytes + 255) & ~(size_t)255;
        return p;
    };
    // zeroed region first (one memset): cnt + partials + scan state
    int*   cnt      = (int*)alloc(NN * sizeof(int));
    float* partials = (float*)alloc(3 * 2048 * sizeof(float));
    int*   sums     = (int*)alloc(NB_SCAN * sizeof(int));
    int*   prefixes = (int*)alloc(NB_SCAN * sizeof(int));
    int*   flags    = (int*)alloc(NB_SCAN * sizeof(int));
    size_t zero_span = off;
    u32*   slot    = (u32*)alloc((size_t)EE * sizeof(u32));
    int*   rowptr  = (int*)alloc((NN + 1) * sizeof(int));
    uint2* edges   = (uint2*)alloc((size_t)EE * sizeof(uint2));
    u32*   h       = (u32*)alloc((size_t)NN * HQ * sizeof(u32));
    u32*   g       = (u32*)alloc((size_t)NN * HQ * sizeof(u32));
    u32*   xh      = (u32*)alloc((size_t)NN * HQ * sizeof(u32));
    float* al_s    = (float*)alloc((size_t)NN * NH * sizeof(float));
    float* al_d    = (float*)alloc((size_t)NN * NH * sizeof(float));
    float* wedot   = (float*)alloc(16 * sizeof(float));
    float* wf      = (float*)alloc(34 * HID * sizeof(float));
    float* wga     = (float*)alloc(HID * 8 * sizeof(float));
    u32*   wb      = (u32*)alloc((size_t)2 * WB_LSZ * sizeof(u32));
    u32*   wb2     = (u32*)alloc(17 * 64 * 4 * sizeof(u32));
    (void)ws_size; (void)n_in; (void)in_sizes; (void)out_size;

    hipMemsetAsync(d_ws, 0, zero_span, stream);
    // A: hist (8 edges/thread) || weight prep
    hist_prep_kernel<<<HB8 + 36, 256, 0, stream>>>(ei, cnt, slot, We, a_edge, wedot,
                                                   Win, b_in, Wg, wf, a_src, a_dst,
                                                   wb, wga);
    // B: single-pass scan (decoupled lookback) || prep2
    scan_prep2_kernel<<<NB_SCAN + 18, 1024, 0, stream>>>(cnt, rowptr, sums, prefixes,
                                                         flags, Win, b_in, wga, wf, wb2);
    // C: scatter (8 edges/thread) || layer-0 MFMA GEMM
    scatter_ingemm_kernel<<<SB8 + NG64, 256, 0, stream>>>(ei, ea, rowptr, slot, edges,
                                                          x, wb2, wf, b_in, h, xh,
                                                          al_s, al_d);
    for (int l = 0; l < NL; l++) {
        if (l > 0) {
            gemm_mfma_kernel<<<NG64, 256, 0, stream>>>(
                h, wb + (size_t)(l - 1) * WB_LSZ, xh, g,
                ln_w + (size_t)(l - 1) * HID, ln_b + (size_t)(l - 1) * HID,
                partials + (size_t)(l - 1) * 2048, h, al_s, al_d);
        }
        gat_agg_kernel<<<(NN + 31) / 32, 256, 0, stream>>>(
            rowptr, edges, xh, al_s, al_d, wedot + l * 4,
            bg + (size_t)l * HID, g, partials + (size_t)l * 2048);
    }

    ln_out_kernel<<<(NN + 15) / 16, 256, 0, stream>>>(g, h, ln_w + (size_t)2 * HID,
                                                      ln_b + (size_t)2 * HID,
                                                      partials + 2 * 2048, Wout, bout, out);
}